// Round 11
// baseline (358.942 us; speedup 1.0000x reference)
//
#include <hip/hip_runtime.h>
#include <stdint.h>

#define B_  8
#define C_  512
#define H_  96
#define W_  96
#define CQ_ 64
#define P_  (H_*W_)     // 9216 pixels per batch
#define NP  (B_*P_)     // 73728
#define L_  (W_+H_)     // 192 logits per pixel

typedef __attribute__((ext_vector_type(8))) short short8;
typedef __attribute__((ext_vector_type(4))) float f32x4;
typedef __attribute__((ext_vector_type(4))) unsigned short us4;

__device__ __forceinline__ ushort f2bf(float f) {
    uint32_t u = __builtin_bit_cast(uint32_t, f);
    u += 0x7fff + ((u >> 16) & 1);
    return (ushort)(u >> 16);
}
__device__ __forceinline__ float bf2f(ushort h) {
    uint32_t u = ((uint32_t)h) << 16;
    return __builtin_bit_cast(float, u);
}

// global -> LDS direct 16B copy (dest = wave-uniform base + lane*16)
#define GLL16(g, l) __builtin_amdgcn_global_load_lds( \
    (const __attribute__((address_space(1))) uint32_t*)(g), \
    (__attribute__((address_space(3))) uint32_t*)(l), 16, 0, 0)

// chunk swizzle for GEMM staging (proven r6): reads use ck = gq^FSW(rr)
#define FSW(r) (((r) >> 1) & 3)

// transpose-buffer group swizzle (r9): element (r,c) of a 96x96 plane at
// t[r*128 + (((c>>2) ^ ((r>>2)&7))<<2) + (c&3)]
__device__ __forceinline__ int TSW(int r, int c) {
    return r * 128 + ((((c >> 2) ^ ((r >> 2) & 7))) << 2) + (c & 3);
}

// ---------------- K0a: x (b,c,p) fp32 -> x_t (b,p,c) bf16 ----------------
__global__ __launch_bounds__(256) void k_xt(const float* __restrict__ x, ushort* __restrict__ xt) {
    __shared__ float tile[64 * 67];                    // pad 67: read bank-step 12 -> 2-way
    int p0 = blockIdx.x * 64, c0 = blockIdx.y * 64, bat = blockIdx.z;
    int tid = threadIdx.x;
    const float* xb = x + ((size_t)bat * C_ + c0) * P_ + p0;
    #pragma unroll
    for (int k = 0; k < 4; ++k) {                      // 64 c-rows x 16 float4
        int u = tid + k * 256, row = u >> 4, p4 = (u & 15) * 4;
        float4 v = *(const float4*)&xb[(size_t)row * P_ + p4];
        tile[row * 67 + p4]     = v.x;
        tile[row * 67 + p4 + 1] = v.y;
        tile[row * 67 + p4 + 2] = v.z;
        tile[row * 67 + p4 + 3] = v.w;
    }
    __syncthreads();
    ushort* o = xt + ((size_t)bat * P_ + p0) * C_ + c0;
    #pragma unroll
    for (int k = 0; k < 4; ++k) {                      // 64 p-rows x 16 us4 (c)
        int u = tid + k * 256, p = u >> 4, c4 = (u & 15) * 4;
        us4 v;
        v.x = f2bf(tile[(c4 + 0) * 67 + p]);
        v.y = f2bf(tile[(c4 + 1) * 67 + p]);
        v.z = f2bf(tile[(c4 + 2) * 67 + p]);
        v.w = f2bf(tile[(c4 + 3) * 67 + p]);
        *(us4*)&o[(size_t)p * C_ + c4] = v;
    }
}

// ---------------- K0b: weights -> bf16 combined [640][512]; ball[640] ----------------
__global__ __launch_bounds__(256) void k_wconv(const float* __restrict__ Wq, const float* __restrict__ Wk,
                                               const float* __restrict__ Wv, const float* __restrict__ bq,
                                               const float* __restrict__ bk, const float* __restrict__ bv,
                                               ushort* __restrict__ Wall, float* __restrict__ ball) {
    int idx = blockIdx.x * 256 + threadIdx.x;
    if (idx < 640) {
        float b;
        if (idx < 64)       b = bq[idx];
        else if (idx < 128) b = bk[idx - 64];
        else                b = bv[idx - 128];
        ball[idx] = b;
    }
    if (idx >= 640 * C_) return;
    int o = idx / C_, c = idx % C_;
    float v;
    if (o < 64)       v = Wq[o * C_ + c];
    else if (o < 128) v = Wk[(o - 64) * C_ + c];
    else              v = Wv[(o - 128) * C_ + c];
    Wall[idx] = f2bf(v);
}

// ---------------- K1: projection GEMM. M=640(o) x N=NP(pix), K=512, tile 128x128. ----------------
// LDS union SB: K-loop staging (Al|Bl) aliases epilogue transpose buffers.
// Q/K blocks: Tl [col][o] -> pixel-major us4 writes. V blocks (NEW): Tl2 [o][col]
// -> channel-major 256B-contiguous us4 writes (was 64 scalar 2B stores/thread).
__global__ __launch_bounds__(256, 4) void k_proj(const ushort* __restrict__ xt, const ushort* __restrict__ Wall,
                                                 const float* __restrict__ ball,
                                                 ushort* __restrict__ Qb, ushort* __restrict__ Kb,
                                                 ushort* __restrict__ Vcm) {
    __shared__ __align__(16) ushort SB[128 * 68];     // 17.4KB union
    ushort* Al  = SB;                                  // [128][32] 8KB (K-loop)
    ushort* Bl  = SB + 128 * 32;                       // [128][32] 8KB (K-loop)
    ushort* Tl  = SB;                                  // [128][68] Q/K epilogue [col][o]
    ushort* Tl2 = SB;                                  // [64][132] V epilogue [o][col], 16.9KB
    int tid = threadIdx.x, lane = tid & 63, wv = tid >> 6;
    int wr = wv >> 1, wc = wv & 1;
    int wg = ((int)blockIdx.x & 7) * 360 + ((int)blockIdx.x >> 3);
    int m0 = (wg % 5) * 128;
    int n0 = (wg / 5) * 128;
    f32x4 acc[4][4] = {};
    for (int kb = 0; kb < C_; kb += 32) {
        #pragma unroll
        for (int i = 0; i < 2; ++i) {
            int u = tid + i * 256, row = u >> 2, seg = u & 3;
            int sg = (seg ^ FSW(row)) << 3;
            GLL16(&Wall[(size_t)(m0 + row) * C_ + kb + sg], &Al[(size_t)u * 8]);
            GLL16(&xt[(size_t)(n0 + row) * C_ + kb + sg],   &Bl[(size_t)u * 8]);
        }
        __syncthreads();
        int rr = lane & 15, gq = lane >> 4, ck = gq ^ FSW(rr);
        short8 fb[4];
        #pragma unroll
        for (int nt = 0; nt < 4; ++nt) fb[nt] = *(const short8*)&Bl[(wc * 64 + nt * 16 + rr) * 32 + ck * 8];
        #pragma unroll
        for (int mt = 0; mt < 4; ++mt) {
            short8 fa = *(const short8*)&Al[(wr * 64 + mt * 16 + rr) * 32 + ck * 8];
            #pragma unroll
            for (int nt = 0; nt < 4; ++nt)
                acc[mt][nt] = __builtin_amdgcn_mfma_f32_16x16x32_bf16(fa, fb[nt], acc[mt][nt], 0, 0, 0);
        }
        __syncthreads();
    }
    int rr = lane & 15, gq = lane >> 4;
    int bat = n0 / P_, pb0 = n0 - bat * P_;
    if (m0 == 0) {
        // Q (wr==0) then K (wr==1): LDS-transpose -> pixel-major coalesced us4 writes
        #pragma unroll
        for (int pass = 0; pass < 2; ++pass) {
            __syncthreads();
            if (wr == pass) {
                #pragma unroll
                for (int mt = 0; mt < 4; ++mt)
                    #pragma unroll
                    for (int nt = 0; nt < 4; ++nt) {
                        int col = wc * 64 + nt * 16 + rr;
                        #pragma unroll
                        for (int q = 0; q < 4; ++q) {
                            int ol = mt * 16 + gq * 4 + q;           // 0..63
                            Tl[col * 68 + ol] = f2bf(acc[mt][nt][q] + ball[pass * 64 + ol]);
                        }
                    }
            }
            __syncthreads();
            ushort* dst = pass ? Kb : Qb;
            int p = tid >> 1, off = (tid & 1) * 32;
            #pragma unroll
            for (int j = 0; j < 8; ++j)
                *(us4*)&dst[(size_t)(n0 + p) * CQ_ + off + j * 4] = *(const us4*)&Tl[p * 68 + off + j * 4];
        }
    } else {
        // V: 2 passes of 64 channels. Tl2[ol][col] -> 256B-contiguous rows of Vcm.
        int c0 = m0 - 128;
        #pragma unroll
        for (int pass = 0; pass < 2; ++pass) {
            __syncthreads();
            if (wr == pass) {
                #pragma unroll
                for (int mt = 0; mt < 4; ++mt)
                    #pragma unroll
                    for (int nt = 0; nt < 4; ++nt) {
                        int col = wc * 64 + nt * 16 + rr;
                        #pragma unroll
                        for (int q = 0; q < 4; ++q) {
                            int ol = mt * 16 + gq * 4 + q;           // 0..63
                            Tl2[ol * 132 + col] = f2bf(acc[mt][nt][q] + ball[m0 + pass * 64 + ol]);
                        }
                    }
            }
            __syncthreads();
            int cl = tid >> 2, q32 = (tid & 3) * 32;                 // 64 c-rows x 4 quarters
            size_t vrow = ((size_t)bat * C_ + c0 + pass * 64 + cl) * P_ + pb0 + q32;
            #pragma unroll
            for (int j = 0; j < 8; ++j)
                *(us4*)&Vcm[vrow + j * 4] = *(const us4*)&Tl2[cl * 132 + q32 + j * 4];
        }
    }
}

// ---------------- K3: Vcm (b,c,h,w) -> Vt (b,w,c,h); one plane per block, swizzled LDS ----------------
__global__ __launch_bounds__(256) void k_vt(const ushort* __restrict__ Vcm, ushort* __restrict__ Vt) {
    __shared__ ushort t[96 * 128];                     // group-XOR swizzled plane
    int c = blockIdx.x, bat = blockIdx.y;
    const ushort* src = Vcm + ((size_t)(bat * C_ + c)) * P_;
    int tid = threadIdx.x;
    #pragma unroll
    for (int k = 0; k < 9; ++k) {                      // 96 h x 24 us4 of w
        int u = tid + k * 256, h = u / 24, w4 = (u % 24) * 4;
        us4 v = *(const us4*)&src[h * 96 + w4];
        t[TSW(h, w4)]     = v.x;
        t[TSW(h, w4) + 1] = v.y;
        t[TSW(h, w4) + 2] = v.z;
        t[TSW(h, w4) + 3] = v.w;
    }
    __syncthreads();
    #pragma unroll
    for (int k = 0; k < 9; ++k) {                      // 96 w x 24 us4 of h
        int u = tid + k * 256, w = u / 24, h4 = (u % 24) * 4;
        us4 o;
        o.x = t[TSW(h4 + 0, w)];
        o.y = t[TSW(h4 + 1, w)];
        o.z = t[TSW(h4 + 2, w)];
        o.w = t[TSW(h4 + 3, w)];
        *(us4*)&Vt[((size_t)(bat * W_ + w) * C_ + c) * H_ + h4] = o;
    }
}

// ---------------- K4: e_row. block (h,b): M=96(w) N=96(v) K=64; bf16 into attn[pix][0:96] ----------------
#define LSTR 40
__global__ __launch_bounds__(256) void k_erow(const ushort* __restrict__ Qb, const ushort* __restrict__ Kb,
                                              ushort* __restrict__ attn) {
    __shared__ __align__(16) ushort Al[96 * LSTR];
    __shared__ __align__(16) ushort Bl[96 * LSTR];
    int h = blockIdx.x, bat = blockIdx.y;
    int tid = threadIdx.x, lane = tid & 63, wvid = tid >> 6;
    int wr = wvid >> 1, wc = wvid & 1;                 // wave tile 48x48
    size_t base = ((size_t)bat * H_ + h) * W_;
    f32x4 acc[3][3] = {};
    for (int kb = 0; kb < CQ_; kb += 32) {
        for (int s = tid; s < 96 * 4; s += 256) {
            int row = s >> 2, seg = s & 3;
            *(short8*)&Al[row * LSTR + seg * 8] = *(const short8*)&Qb[(base + row) * CQ_ + kb + seg * 8];
            *(short8*)&Bl[row * LSTR + seg * 8] = *(const short8*)&Kb[(base + row) * CQ_ + kb + seg * 8];
        }
        __syncthreads();
        int rr = lane & 15, gq = lane >> 4;
        #pragma unroll
        for (int mt = 0; mt < 3; ++mt) {
            short8 fa = *(const short8*)&Al[(wr * 48 + mt * 16 + rr) * LSTR + gq * 8];
            #pragma unroll
            for (int nt = 0; nt < 3; ++nt) {
                short8 fb = *(const short8*)&Bl[(wc * 48 + nt * 16 + rr) * LSTR + gq * 8];
                acc[mt][nt] = __builtin_amdgcn_mfma_f32_16x16x32_bf16(fa, fb, acc[mt][nt], 0, 0, 0);
            }
        }
        __syncthreads();
    }
    int rr = lane & 15, gq = lane >> 4;
    #pragma unroll
    for (int mt = 0; mt < 3; ++mt)
        #pragma unroll
        for (int nt = 0; nt < 3; ++nt)
            #pragma unroll
            for (int q = 0; q < 4; ++q) {
                int w = wr * 48 + mt * 16 + gq * 4 + q;
                int v = wc * 48 + nt * 16 + rr;
                attn[(base + w) * L_ + v] = f2bf(acc[mt][nt][q]);
            }
}

// ---------------- K5: e_col GEMM + fused softmax (in-place on attn). block (w,b). ----------------
__global__ __launch_bounds__(256) void k_ecolsm(const ushort* __restrict__ Qb, const ushort* __restrict__ Kb,
                                                ushort* __restrict__ attn) {
    __shared__ __align__(16) ushort Al[96 * LSTR];
    __shared__ __align__(16) ushort Bl[96 * LSTR];
    __shared__ ushort ecl[96 * 100];                   // [h][g] bf16, padded
    int w = blockIdx.x, bat = blockIdx.y;
    int tid = threadIdx.x, lane = tid & 63, wvid = tid >> 6;
    int wr = wvid >> 1, wc = wvid & 1;
    f32x4 acc[3][3] = {};
    for (int kb = 0; kb < CQ_; kb += 32) {
        for (int s = tid; s < 96 * 4; s += 256) {
            int row = s >> 2, seg = s & 3;
            size_t px = ((size_t)bat * H_ + row) * W_ + w;
            *(short8*)&Al[row * LSTR + seg * 8] = *(const short8*)&Qb[px * CQ_ + kb + seg * 8];
            *(short8*)&Bl[row * LSTR + seg * 8] = *(const short8*)&Kb[px * CQ_ + kb + seg * 8];
        }
        __syncthreads();
        int rr = lane & 15, gq = lane >> 4;
        #pragma unroll
        for (int mt = 0; mt < 3; ++mt) {
            short8 fa = *(const short8*)&Al[(wr * 48 + mt * 16 + rr) * LSTR + gq * 8];
            #pragma unroll
            for (int nt = 0; nt < 3; ++nt) {
                short8 fb = *(const short8*)&Bl[(wc * 48 + nt * 16 + rr) * LSTR + gq * 8];
                acc[mt][nt] = __builtin_amdgcn_mfma_f32_16x16x32_bf16(fa, fb, acc[mt][nt], 0, 0, 0);
            }
        }
        __syncthreads();
    }
    {
        int rr = lane & 15, gq = lane >> 4;
        #pragma unroll
        for (int mt = 0; mt < 3; ++mt)
            #pragma unroll
            for (int nt = 0; nt < 3; ++nt)
                #pragma unroll
                for (int q = 0; q < 4; ++q) {
                    int hh = wr * 48 + mt * 16 + gq * 4 + q;
                    int gg = wc * 48 + nt * 16 + rr;
                    ecl[hh * 100 + gg] = f2bf(acc[mt][nt][q]);
                }
    }
    __syncthreads();
    for (int h = wvid; h < H_; h += 4) {
        size_t pix = ((size_t)bat * H_ + h) * W_ + w;
        ushort* ap = attn + pix * L_;
        float a  = bf2f(ap[lane]);
        float b  = (lane < 32) ? bf2f(ap[64 + lane]) : -1e30f;
        float c0 = bf2f(ecl[h * 100 + lane]);
        float c1 = (lane < 32) ? bf2f(ecl[h * 100 + 64 + lane]) : -1e30f;
        float m = fmaxf(fmaxf(a, b), fmaxf(c0, c1));
        #pragma unroll
        for (int off = 32; off; off >>= 1) m = fmaxf(m, __shfl_xor(m, off));
        float ea = __expf(a - m), eb = (lane < 32) ? __expf(b - m) : 0.0f;
        float ec0 = __expf(c0 - m), ec1 = (lane < 32) ? __expf(c1 - m) : 0.0f;
        float s = ea + eb + ec0 + ec1;
        #pragma unroll
        for (int off = 32; off; off >>= 1) s += __shfl_xor(s, off);
        float inv = 1.0f / s;
        ap[lane] = f2bf(ea * inv);
        ap[96 + lane] = f2bf(ec0 * inv);
        if (lane < 32) {
            ap[64 + lane] = f2bf(eb * inv);
            ap[160 + lane] = f2bf(ec1 * inv);
        }
    }
}

// ---------------- K8: col PV. block (w,b): M=512(c) N=96(h) K=96(g); out (b,c,w,h) ----------------
__global__ __launch_bounds__(512) void k_pvcol(const ushort* __restrict__ Vt, const ushort* __restrict__ attn,
                                               ushort* __restrict__ out1t) {
    __shared__ __align__(16) ushort Al[512 * 32];     // [c][g] 32KB linear
    __shared__ __align__(16) ushort Bl[96 * 32];      // [h][g] 6KB linear
    int w = blockIdx.x, bat = blockIdx.y;
    int tid = threadIdx.x, lane = tid & 63, wvid = tid >> 6;
    int wrm = wvid >> 1, wcn = wvid & 1;              // 4m x 2n, wave tile 128x48
    size_t vbase = ((size_t)bat * W_ + w) * C_ * H_;
    size_t abase = ((size_t)bat * P_ + w) * L_ + W_;
    f32x4 acc[8][3] = {};
    for (int kb = 0; kb < 96; kb += 32) {
        #pragma unroll
        for (int i = 0; i < 4; ++i) {
            int u = tid + i * 512, row = u >> 2, seg = u & 3;
            int sg = (seg ^ FSW(row)) << 3;
            GLL16(&Vt[vbase + (size_t)row * H_ + kb + sg], &Al[(size_t)u * 8]);
        }
        if (tid < 384) {
            int row = tid >> 2, seg = tid & 3;
            int sg = (seg ^ FSW(row)) << 3;
            GLL16(&attn[abase + (size_t)row * (W_ * L_) + kb + sg], &Bl[(size_t)tid * 8]);
        }
        __syncthreads();
        int rr = lane & 15, gq = lane >> 4, ck = gq ^ FSW(rr);
        short8 fb[3];
        #pragma unroll
        for (int nt = 0; nt < 3; ++nt) fb[nt] = *(const short8*)&Bl[(wcn * 48 + nt * 16 + rr) * 32 + ck * 8];
        #pragma unroll
        for (int mt = 0; mt < 8; ++mt) {
            short8 fa = *(const short8*)&Al[(wrm * 128 + mt * 16 + rr) * 32 + ck * 8];
            #pragma unroll
            for (int nt = 0; nt < 3; ++nt)
                acc[mt][nt] = __builtin_amdgcn_mfma_f32_16x16x32_bf16(fa, fb[nt], acc[mt][nt], 0, 0, 0);
        }
        __syncthreads();
    }
    int rr = lane & 15, gq = lane >> 4;
    #pragma unroll
    for (int mt = 0; mt < 8; ++mt)
        #pragma unroll
        for (int nt = 0; nt < 3; ++nt) {
            int hh = wcn * 48 + nt * 16 + rr;
            #pragma unroll
            for (int q = 0; q < 4; ++q) {
                int c = wrm * 128 + mt * 16 + gq * 4 + q;
                out1t[((size_t)(bat * C_ + c) * W_ + w) * H_ + hh] = f2bf(acc[mt][nt][q]);
            }
        }
}

// ---------------- K7: row PV. block (h,b): M=512(c) N=96(w) K=96(v) ----------------
__global__ __launch_bounds__(512) void k_pvrow(const ushort* __restrict__ Vcm, const ushort* __restrict__ attn,
                                               ushort* __restrict__ out0) {
    __shared__ __align__(16) ushort Al[512 * 32];     // [c][v] 32KB
    __shared__ __align__(16) ushort Bl[96 * 32];      // [w][v] 6KB
    int h = blockIdx.x, bat = blockIdx.y;
    int tid = threadIdx.x, lane = tid & 63, wvid = tid >> 6;
    int wrm = wvid >> 1, wcn = wvid & 1;
    size_t vbase = (size_t)bat * C_ * P_ + (size_t)h * W_;
    size_t abase = ((size_t)bat * H_ + h) * W_ * L_;
    f32x4 acc[8][3] = {};
    for (int kb = 0; kb < 96; kb += 32) {
        #pragma unroll
        for (int i = 0; i < 4; ++i) {
            int u = tid + i * 512, row = u >> 2, seg = u & 3;
            int sg = (seg ^ FSW(row)) << 3;
            GLL16(&Vcm[vbase + (size_t)row * P_ + kb + sg], &Al[(size_t)u * 8]);
        }
        if (tid < 384) {
            int row = tid >> 2, seg = tid & 3;
            int sg = (seg ^ FSW(row)) << 3;
            GLL16(&attn[abase + (size_t)row * L_ + kb + sg], &Bl[(size_t)tid * 8]);
        }
        __syncthreads();
        int rr = lane & 15, gq = lane >> 4, ck = gq ^ FSW(rr);
        short8 fb[3];
        #pragma unroll
        for (int nt = 0; nt < 3; ++nt) fb[nt] = *(const short8*)&Bl[(wcn * 48 + nt * 16 + rr) * 32 + ck * 8];
        #pragma unroll
        for (int mt = 0; mt < 8; ++mt) {
            short8 fa = *(const short8*)&Al[(wrm * 128 + mt * 16 + rr) * 32 + ck * 8];
            #pragma unroll
            for (int nt = 0; nt < 3; ++nt)
                acc[mt][nt] = __builtin_amdgcn_mfma_f32_16x16x32_bf16(fa, fb[nt], acc[mt][nt], 0, 0, 0);
        }
        __syncthreads();
    }
    int rr = lane & 15, gq = lane >> 4;
    #pragma unroll
    for (int mt = 0; mt < 8; ++mt)
        #pragma unroll
        for (int nt = 0; nt < 3; ++nt) {
            int w = wcn * 48 + nt * 16 + rr;
            #pragma unroll
            for (int q = 0; q < 4; ++q) {
                int c = wrm * 128 + mt * 16 + gq * 4 + q;
                out0[((size_t)bat * C_ + c) * P_ + (size_t)h * W_ + w] = f2bf(acc[mt][nt][q]);
            }
        }
}

// ---------------- K9: out = x + gamma*(out0 + out1t^T), swizzled transpose LDS ----------------
__global__ __launch_bounds__(256) void k_final(const float* __restrict__ x, const ushort* __restrict__ out0,
                                               const ushort* __restrict__ out1t, const float* __restrict__ gamma,
                                               float* __restrict__ out) {
    __shared__ ushort t[96 * 128];                     // group-XOR swizzled [h][w] plane
    int c = blockIdx.x, bat = blockIdx.y;
    const ushort* src = out1t + ((size_t)bat * C_ + c) * P_;   // plane [w][h]
    int tid = threadIdx.x;
    #pragma unroll
    for (int k = 0; k < 9; ++k) {                      // 96 w x 24 us4 of h
        int u = tid + k * 256, w = u / 24, h4 = (u % 24) * 4;
        us4 v = *(const us4*)&src[w * 96 + h4];
        t[TSW(h4 + 0, w)] = v.x;
        t[TSW(h4 + 1, w)] = v.y;
        t[TSW(h4 + 2, w)] = v.z;
        t[TSW(h4 + 3, w)] = v.w;
    }
    __syncthreads();
    float gm = gamma[0];
    size_t base = ((size_t)bat * C_ + c) * P_;
    #pragma unroll
    for (int k = 0; k < 9; ++k) {                      // 96 h x 24 us4 of w
        int u = tid + k * 256, h = u / 24, w4 = (u % 24) * 4;
        size_t idx = base + h * W_ + w4;
        float4 xv = *(const float4*)&x[idx];
        us4 o0 = *(const us4*)&out0[idx];
        us4 o1 = *(const us4*)&t[TSW(h, w4)];
        float4 r;
        r.x = xv.x + gm * (bf2f(o0.x) + bf2f(o1.x));
        r.y = xv.y + gm * (bf2f(o0.y) + bf2f(o1.y));
        r.z = xv.z + gm * (bf2f(o0.z) + bf2f(o1.z));
        r.w = xv.w + gm * (bf2f(o0.w) + bf2f(o1.w));
        *(float4*)&out[idx] = r;
    }
}

extern "C" void kernel_launch(void* const* d_in, const int* in_sizes, int n_in,
                              void* d_out, int out_size, void* d_ws, size_t ws_size,
                              hipStream_t stream) {
    const float* x     = (const float*)d_in[0];
    const float* Wq    = (const float*)d_in[1];
    const float* bq    = (const float*)d_in[2];
    const float* Wk    = (const float*)d_in[3];
    const float* bk    = (const float*)d_in[4];
    const float* Wv    = (const float*)d_in[5];
    const float* bv    = (const float*)d_in[6];
    const float* gamma = (const float*)d_in[7];
    float* out = (float*)d_out;
    char* ws = (char*)d_ws;

    const size_t SZ  = (size_t)NP * C_ * 2;           // 75,497,472 B
    const size_t QKS = (size_t)NP * CQ_ * 2;          // 9,437,184 B
    ushort* xt     = (ushort*)(ws);
    ushort* out1t  = (ushort*)(ws);
    ushort* Vcm    = (ushort*)(ws + SZ);
    ushort* Vt     = (ushort*)(ws + 2 * SZ);
    ushort* out0   = Vt;
    ushort* Qb     = (ushort*)(ws + 3 * SZ);
    ushort* Kb     = (ushort*)(ws + 3 * SZ + QKS);
    ushort* attn   = (ushort*)(ws + 3 * SZ + 2 * QKS);
    size_t off_wall = 3 * SZ + 2 * QKS + (size_t)NP * L_ * 2;
    ushort* Wall   = (ushort*)(ws + off_wall);
    float*  ball   = (float*) (ws + off_wall + 640 * C_ * 2);

    k_wconv  <<<dim3(1280),       dim3(256),   0, stream>>>(Wq, Wk, Wv, bq, bk, bv, Wall, ball);
    k_xt     <<<dim3(144, 8, 8),  dim3(256),   0, stream>>>(x, xt);
    k_proj   <<<dim3(2880),       dim3(256),   0, stream>>>(xt, Wall, ball, Qb, Kb, Vcm);
    k_vt     <<<dim3(512, 8),     dim3(256),   0, stream>>>(Vcm, Vt);
    k_erow   <<<dim3(96, 8),      dim3(256),   0, stream>>>(Qb, Kb, attn);
    k_ecolsm <<<dim3(96, 8),      dim3(256),   0, stream>>>(Qb, Kb, attn);
    k_pvcol  <<<dim3(96, 8),      dim3(512),   0, stream>>>(Vt, attn, out1t);
    k_pvrow  <<<dim3(96, 8),      dim3(512),   0, stream>>>(Vcm, attn, out0);
    k_final  <<<dim3(512, 8),     dim3(256),   0, stream>>>(x, out0, out1t, gamma, out);
}

// Round 12
// 349.478 us; speedup vs baseline: 1.0271x; 1.0271x over previous
//
#include <hip/hip_runtime.h>
#include <stdint.h>

#define B_  8
#define C_  512
#define H_  96
#define W_  96
#define CQ_ 64
#define P_  (H_*W_)     // 9216 pixels per batch
#define NP  (B_*P_)     // 73728
#define L_  (W_+H_)     // 192 logits per pixel

typedef __attribute__((ext_vector_type(8))) short short8;
typedef __attribute__((ext_vector_type(4))) float f32x4;
typedef __attribute__((ext_vector_type(4))) unsigned short us4;

__device__ __forceinline__ ushort f2bf(float f) {
    uint32_t u = __builtin_bit_cast(uint32_t, f);
    u += 0x7fff + ((u >> 16) & 1);
    return (ushort)(u >> 16);
}
__device__ __forceinline__ float bf2f(ushort h) {
    uint32_t u = ((uint32_t)h) << 16;
    return __builtin_bit_cast(float, u);
}

// global -> LDS direct 16B copy (dest = wave-uniform base + lane*16)
#define GLL16(g, l) __builtin_amdgcn_global_load_lds( \
    (const __attribute__((address_space(1))) uint32_t*)(g), \
    (__attribute__((address_space(3))) uint32_t*)(l), 16, 0, 0)

// chunk swizzle for GEMM staging (proven r6): reads use ck = gq^FSW(rr)
#define FSW(r) (((r) >> 1) & 3)

// transpose-buffer group swizzle (r9): element (r,c) of a 96x96 plane at
// t[r*128 + (((c>>2) ^ ((r>>2)&7))<<2) + (c&3)]
__device__ __forceinline__ int TSW(int r, int c) {
    return r * 128 + ((((c >> 2) ^ ((r >> 2) & 7))) << 2) + (c & 3);
}

// ---------------- K0a: x (b,c,p) fp32 -> x_t (b,p,c) bf16 ----------------
__global__ __launch_bounds__(256) void k_xt(const float* __restrict__ x, ushort* __restrict__ xt) {
    __shared__ float tile[64 * 67];                    // pad 67: read bank-step 12 -> 2-way
    int p0 = blockIdx.x * 64, c0 = blockIdx.y * 64, bat = blockIdx.z;
    int tid = threadIdx.x;
    const float* xb = x + ((size_t)bat * C_ + c0) * P_ + p0;
    #pragma unroll
    for (int k = 0; k < 4; ++k) {                      // 64 c-rows x 16 float4
        int u = tid + k * 256, row = u >> 4, p4 = (u & 15) * 4;
        float4 v = *(const float4*)&xb[(size_t)row * P_ + p4];
        tile[row * 67 + p4]     = v.x;
        tile[row * 67 + p4 + 1] = v.y;
        tile[row * 67 + p4 + 2] = v.z;
        tile[row * 67 + p4 + 3] = v.w;
    }
    __syncthreads();
    ushort* o = xt + ((size_t)bat * P_ + p0) * C_ + c0;
    #pragma unroll
    for (int k = 0; k < 4; ++k) {                      // 64 p-rows x 16 us4 (c)
        int u = tid + k * 256, p = u >> 4, c4 = (u & 15) * 4;
        us4 v;
        v.x = f2bf(tile[(c4 + 0) * 67 + p]);
        v.y = f2bf(tile[(c4 + 1) * 67 + p]);
        v.z = f2bf(tile[(c4 + 2) * 67 + p]);
        v.w = f2bf(tile[(c4 + 3) * 67 + p]);
        *(us4*)&o[(size_t)p * C_ + c4] = v;
    }
}

// ---------------- K0b: weights -> bf16 combined [640][512]; ball[640] ----------------
__global__ __launch_bounds__(256) void k_wconv(const float* __restrict__ Wq, const float* __restrict__ Wk,
                                               const float* __restrict__ Wv, const float* __restrict__ bq,
                                               const float* __restrict__ bk, const float* __restrict__ bv,
                                               ushort* __restrict__ Wall, float* __restrict__ ball) {
    int idx = blockIdx.x * 256 + threadIdx.x;
    if (idx < 640) {
        float b;
        if (idx < 64)       b = bq[idx];
        else if (idx < 128) b = bk[idx - 64];
        else                b = bv[idx - 128];
        ball[idx] = b;
    }
    if (idx >= 640 * C_) return;
    int o = idx / C_, c = idx % C_;
    float v;
    if (o < 64)       v = Wq[o * C_ + c];
    else if (o < 128) v = Wk[(o - 64) * C_ + c];
    else              v = Wv[(o - 128) * C_ + c];
    Wall[idx] = f2bf(v);
}

// ---------------- K1: projection GEMM, 2-PHASE double-buffered. ----------------
// M=640(o) x N=NP(pix), K=512, tile 128x128, BK=32. STAGE(t+1) issued BEFORE compute(t);
// ONE barrier per K-step (was 2) -> load latency hidden under MFMA. LDS 32KB (5 blocks/CU).
// Q/K blocks: Tl transpose epilogue (pixel-major us4). V blocks: direct stores (r10-proven).
__global__ __launch_bounds__(256, 4) void k_proj(const ushort* __restrict__ xt, const ushort* __restrict__ Wall,
                                                 const float* __restrict__ ball,
                                                 ushort* __restrict__ Qb, ushort* __restrict__ Kb,
                                                 ushort* __restrict__ Vcm) {
    __shared__ __align__(16) ushort SB[2][2 * 128 * 32];   // [buf][Al|Bl] 32KB
    ushort* Tl = &SB[0][0];                                 // [128][68] epilogue alias (17.4KB)
    int tid = threadIdx.x, lane = tid & 63, wv = tid >> 6;
    int wr = wv >> 1, wc = wv & 1;
    int wg = ((int)blockIdx.x & 7) * 360 + ((int)blockIdx.x >> 3);
    int m0 = (wg % 5) * 128;
    int n0 = (wg / 5) * 128;
    f32x4 acc[4][4] = {};
    // prologue: stage k-step 0 into buf0
    {
        ushort* Al = &SB[0][0]; ushort* Bl = &SB[0][128 * 32];
        #pragma unroll
        for (int i = 0; i < 2; ++i) {
            int u = tid + i * 256, row = u >> 2, seg = u & 3;
            int sg = (seg ^ FSW(row)) << 3;
            GLL16(&Wall[(size_t)(m0 + row) * C_ + sg], &Al[(size_t)u * 8]);
            GLL16(&xt[(size_t)(n0 + row) * C_ + sg],   &Bl[(size_t)u * 8]);
        }
    }
    __syncthreads();
    for (int t = 0; t < 16; ++t) {
        int cur = t & 1;
        if (t < 15) {                                  // issue next-tile loads BEFORE compute
            int kb = (t + 1) * 32;
            ushort* Al = &SB[cur ^ 1][0]; ushort* Bl = &SB[cur ^ 1][128 * 32];
            #pragma unroll
            for (int i = 0; i < 2; ++i) {
                int u = tid + i * 256, row = u >> 2, seg = u & 3;
                int sg = (seg ^ FSW(row)) << 3;
                GLL16(&Wall[(size_t)(m0 + row) * C_ + kb + sg], &Al[(size_t)u * 8]);
                GLL16(&xt[(size_t)(n0 + row) * C_ + kb + sg],   &Bl[(size_t)u * 8]);
            }
        }
        const ushort* Al = &SB[cur][0];
        const ushort* Bl = &SB[cur][128 * 32];
        int rr = lane & 15, gq = lane >> 4, ck = gq ^ FSW(rr);
        short8 fb[4];
        #pragma unroll
        for (int nt = 0; nt < 4; ++nt) fb[nt] = *(const short8*)&Bl[(wc * 64 + nt * 16 + rr) * 32 + ck * 8];
        #pragma unroll
        for (int mt = 0; mt < 4; ++mt) {
            short8 fa = *(const short8*)&Al[(wr * 64 + mt * 16 + rr) * 32 + ck * 8];
            #pragma unroll
            for (int nt = 0; nt < 4; ++nt)
                acc[mt][nt] = __builtin_amdgcn_mfma_f32_16x16x32_bf16(fa, fb[nt], acc[mt][nt], 0, 0, 0);
        }
        __syncthreads();                               // drains stage(t+1) under compute shadow
    }
    int rr = lane & 15, gq = lane >> 4;
    int bat = n0 / P_, pb0 = n0 - bat * P_;
    if (m0 == 0) {
        // Q (wr==0) then K (wr==1): LDS-transpose -> pixel-major coalesced us4 writes
        #pragma unroll
        for (int pass = 0; pass < 2; ++pass) {
            __syncthreads();
            if (wr == pass) {
                #pragma unroll
                for (int mt = 0; mt < 4; ++mt)
                    #pragma unroll
                    for (int nt = 0; nt < 4; ++nt) {
                        int col = wc * 64 + nt * 16 + rr;
                        #pragma unroll
                        for (int q = 0; q < 4; ++q) {
                            int ol = mt * 16 + gq * 4 + q;           // 0..63
                            Tl[col * 68 + ol] = f2bf(acc[mt][nt][q] + ball[pass * 64 + ol]);
                        }
                    }
            }
            __syncthreads();
            ushort* dst = pass ? Kb : Qb;
            int p = tid >> 1, off = (tid & 1) * 32;
            #pragma unroll
            for (int j = 0; j < 8; ++j)
                *(us4*)&dst[(size_t)(n0 + p) * CQ_ + off + j * 4] = *(const us4*)&Tl[p * 68 + off + j * 4];
        }
    } else {
        #pragma unroll
        for (int mt = 0; mt < 4; ++mt)
            #pragma unroll
            for (int nt = 0; nt < 4; ++nt) {
                int col = wc * 64 + nt * 16 + rr;
                #pragma unroll
                for (int q = 0; q < 4; ++q) {
                    int o = m0 + wr * 64 + mt * 16 + gq * 4 + q;     // 128..639
                    int c = o - 128;
                    Vcm[((size_t)bat * C_ + c) * P_ + pb0 + col] = f2bf(acc[mt][nt][q] + ball[o]);
                }
            }
    }
}

// ---------------- K3: Vcm (b,c,h,w) -> Vt (b,w,c,h); one plane per block, swizzled LDS ----------------
__global__ __launch_bounds__(256) void k_vt(const ushort* __restrict__ Vcm, ushort* __restrict__ Vt) {
    __shared__ ushort t[96 * 128];                     // group-XOR swizzled plane
    int c = blockIdx.x, bat = blockIdx.y;
    const ushort* src = Vcm + ((size_t)(bat * C_ + c)) * P_;
    int tid = threadIdx.x;
    #pragma unroll
    for (int k = 0; k < 9; ++k) {                      // 96 h x 24 us4 of w
        int u = tid + k * 256, h = u / 24, w4 = (u % 24) * 4;
        us4 v = *(const us4*)&src[h * 96 + w4];
        t[TSW(h, w4)]     = v.x;
        t[TSW(h, w4) + 1] = v.y;
        t[TSW(h, w4) + 2] = v.z;
        t[TSW(h, w4) + 3] = v.w;
    }
    __syncthreads();
    #pragma unroll
    for (int k = 0; k < 9; ++k) {                      // 96 w x 24 us4 of h
        int u = tid + k * 256, w = u / 24, h4 = (u % 24) * 4;
        us4 o;
        o.x = t[TSW(h4 + 0, w)];
        o.y = t[TSW(h4 + 1, w)];
        o.z = t[TSW(h4 + 2, w)];
        o.w = t[TSW(h4 + 3, w)];
        *(us4*)&Vt[((size_t)(bat * W_ + w) * C_ + c) * H_ + h4] = o;
    }
}

// ---------------- K4: e_row. block (h,b): M=96(w) N=96(v) K=64; bf16 into attn[pix][0:96] ----------------
#define LSTR 40
__global__ __launch_bounds__(256) void k_erow(const ushort* __restrict__ Qb, const ushort* __restrict__ Kb,
                                              ushort* __restrict__ attn) {
    __shared__ __align__(16) ushort Al[96 * LSTR];
    __shared__ __align__(16) ushort Bl[96 * LSTR];
    int h = blockIdx.x, bat = blockIdx.y;
    int tid = threadIdx.x, lane = tid & 63, wvid = tid >> 6;
    int wr = wvid >> 1, wc = wvid & 1;                 // wave tile 48x48
    size_t base = ((size_t)bat * H_ + h) * W_;
    f32x4 acc[3][3] = {};
    for (int kb = 0; kb < CQ_; kb += 32) {
        for (int s = tid; s < 96 * 4; s += 256) {
            int row = s >> 2, seg = s & 3;
            *(short8*)&Al[row * LSTR + seg * 8] = *(const short8*)&Qb[(base + row) * CQ_ + kb + seg * 8];
            *(short8*)&Bl[row * LSTR + seg * 8] = *(const short8*)&Kb[(base + row) * CQ_ + kb + seg * 8];
        }
        __syncthreads();
        int rr = lane & 15, gq = lane >> 4;
        #pragma unroll
        for (int mt = 0; mt < 3; ++mt) {
            short8 fa = *(const short8*)&Al[(wr * 48 + mt * 16 + rr) * LSTR + gq * 8];
            #pragma unroll
            for (int nt = 0; nt < 3; ++nt) {
                short8 fb = *(const short8*)&Bl[(wc * 48 + nt * 16 + rr) * LSTR + gq * 8];
                acc[mt][nt] = __builtin_amdgcn_mfma_f32_16x16x32_bf16(fa, fb, acc[mt][nt], 0, 0, 0);
            }
        }
        __syncthreads();
    }
    int rr = lane & 15, gq = lane >> 4;
    #pragma unroll
    for (int mt = 0; mt < 3; ++mt)
        #pragma unroll
        for (int nt = 0; nt < 3; ++nt)
            #pragma unroll
            for (int q = 0; q < 4; ++q) {
                int w = wr * 48 + mt * 16 + gq * 4 + q;
                int v = wc * 48 + nt * 16 + rr;
                attn[(base + w) * L_ + v] = f2bf(acc[mt][nt][q]);
            }
}

// ---------------- K5: e_col GEMM + fused softmax (in-place on attn). block (w,b). ----------------
__global__ __launch_bounds__(256) void k_ecolsm(const ushort* __restrict__ Qb, const ushort* __restrict__ Kb,
                                                ushort* __restrict__ attn) {
    __shared__ __align__(16) ushort Al[96 * LSTR];
    __shared__ __align__(16) ushort Bl[96 * LSTR];
    __shared__ ushort ecl[96 * 100];                   // [h][g] bf16, padded
    int w = blockIdx.x, bat = blockIdx.y;
    int tid = threadIdx.x, lane = tid & 63, wvid = tid >> 6;
    int wr = wvid >> 1, wc = wvid & 1;
    f32x4 acc[3][3] = {};
    for (int kb = 0; kb < CQ_; kb += 32) {
        for (int s = tid; s < 96 * 4; s += 256) {
            int row = s >> 2, seg = s & 3;
            size_t px = ((size_t)bat * H_ + row) * W_ + w;
            *(short8*)&Al[row * LSTR + seg * 8] = *(const short8*)&Qb[px * CQ_ + kb + seg * 8];
            *(short8*)&Bl[row * LSTR + seg * 8] = *(const short8*)&Kb[px * CQ_ + kb + seg * 8];
        }
        __syncthreads();
        int rr = lane & 15, gq = lane >> 4;
        #pragma unroll
        for (int mt = 0; mt < 3; ++mt) {
            short8 fa = *(const short8*)&Al[(wr * 48 + mt * 16 + rr) * LSTR + gq * 8];
            #pragma unroll
            for (int nt = 0; nt < 3; ++nt) {
                short8 fb = *(const short8*)&Bl[(wc * 48 + nt * 16 + rr) * LSTR + gq * 8];
                acc[mt][nt] = __builtin_amdgcn_mfma_f32_16x16x32_bf16(fa, fb, acc[mt][nt], 0, 0, 0);
            }
        }
        __syncthreads();
    }
    {
        int rr = lane & 15, gq = lane >> 4;
        #pragma unroll
        for (int mt = 0; mt < 3; ++mt)
            #pragma unroll
            for (int nt = 0; nt < 3; ++nt)
                #pragma unroll
                for (int q = 0; q < 4; ++q) {
                    int hh = wr * 48 + mt * 16 + gq * 4 + q;
                    int gg = wc * 48 + nt * 16 + rr;
                    ecl[hh * 100 + gg] = f2bf(acc[mt][nt][q]);
                }
    }
    __syncthreads();
    for (int h = wvid; h < H_; h += 4) {
        size_t pix = ((size_t)bat * H_ + h) * W_ + w;
        ushort* ap = attn + pix * L_;
        float a  = bf2f(ap[lane]);
        float b  = (lane < 32) ? bf2f(ap[64 + lane]) : -1e30f;
        float c0 = bf2f(ecl[h * 100 + lane]);
        float c1 = (lane < 32) ? bf2f(ecl[h * 100 + 64 + lane]) : -1e30f;
        float m = fmaxf(fmaxf(a, b), fmaxf(c0, c1));
        #pragma unroll
        for (int off = 32; off; off >>= 1) m = fmaxf(m, __shfl_xor(m, off));
        float ea = __expf(a - m), eb = (lane < 32) ? __expf(b - m) : 0.0f;
        float ec0 = __expf(c0 - m), ec1 = (lane < 32) ? __expf(c1 - m) : 0.0f;
        float s = ea + eb + ec0 + ec1;
        #pragma unroll
        for (int off = 32; off; off >>= 1) s += __shfl_xor(s, off);
        float inv = 1.0f / s;
        ap[lane] = f2bf(ea * inv);
        ap[96 + lane] = f2bf(ec0 * inv);
        if (lane < 32) {
            ap[64 + lane] = f2bf(eb * inv);
            ap[160 + lane] = f2bf(ec1 * inv);
        }
    }
}

// ---------------- K8: col PV. block (w,b): M=512(c) N=96(h) K=96(g); out (b,c,w,h) ----------------
__global__ __launch_bounds__(512) void k_pvcol(const ushort* __restrict__ Vt, const ushort* __restrict__ attn,
                                               ushort* __restrict__ out1t) {
    __shared__ __align__(16) ushort Al[512 * 32];     // [c][g] 32KB linear
    __shared__ __align__(16) ushort Bl[96 * 32];      // [h][g] 6KB linear
    int w = blockIdx.x, bat = blockIdx.y;
    int tid = threadIdx.x, lane = tid & 63, wvid = tid >> 6;
    int wrm = wvid >> 1, wcn = wvid & 1;              // 4m x 2n, wave tile 128x48
    size_t vbase = ((size_t)bat * W_ + w) * C_ * H_;
    size_t abase = ((size_t)bat * P_ + w) * L_ + W_;
    f32x4 acc[8][3] = {};
    for (int kb = 0; kb < 96; kb += 32) {
        #pragma unroll
        for (int i = 0; i < 4; ++i) {
            int u = tid + i * 512, row = u >> 2, seg = u & 3;
            int sg = (seg ^ FSW(row)) << 3;
            GLL16(&Vt[vbase + (size_t)row * H_ + kb + sg], &Al[(size_t)u * 8]);
        }
        if (tid < 384) {
            int row = tid >> 2, seg = tid & 3;
            int sg = (seg ^ FSW(row)) << 3;
            GLL16(&attn[abase + (size_t)row * (W_ * L_) + kb + sg], &Bl[(size_t)tid * 8]);
        }
        __syncthreads();
        int rr = lane & 15, gq = lane >> 4, ck = gq ^ FSW(rr);
        short8 fb[3];
        #pragma unroll
        for (int nt = 0; nt < 3; ++nt) fb[nt] = *(const short8*)&Bl[(wcn * 48 + nt * 16 + rr) * 32 + ck * 8];
        #pragma unroll
        for (int mt = 0; mt < 8; ++mt) {
            short8 fa = *(const short8*)&Al[(wrm * 128 + mt * 16 + rr) * 32 + ck * 8];
            #pragma unroll
            for (int nt = 0; nt < 3; ++nt)
                acc[mt][nt] = __builtin_amdgcn_mfma_f32_16x16x32_bf16(fa, fb[nt], acc[mt][nt], 0, 0, 0);
        }
        __syncthreads();
    }
    int rr = lane & 15, gq = lane >> 4;
    #pragma unroll
    for (int mt = 0; mt < 8; ++mt)
        #pragma unroll
        for (int nt = 0; nt < 3; ++nt) {
            int hh = wcn * 48 + nt * 16 + rr;
            #pragma unroll
            for (int q = 0; q < 4; ++q) {
                int c = wrm * 128 + mt * 16 + gq * 4 + q;
                out1t[((size_t)(bat * C_ + c) * W_ + w) * H_ + hh] = f2bf(acc[mt][nt][q]);
            }
        }
}

// ---------------- K7: row PV. block (h,b): M=512(c) N=96(w) K=96(v) ----------------
__global__ __launch_bounds__(512) void k_pvrow(const ushort* __restrict__ Vcm, const ushort* __restrict__ attn,
                                               ushort* __restrict__ out0) {
    __shared__ __align__(16) ushort Al[512 * 32];     // [c][v] 32KB
    __shared__ __align__(16) ushort Bl[96 * 32];      // [w][v] 6KB
    int h = blockIdx.x, bat = blockIdx.y;
    int tid = threadIdx.x, lane = tid & 63, wvid = tid >> 6;
    int wrm = wvid >> 1, wcn = wvid & 1;
    size_t vbase = (size_t)bat * C_ * P_ + (size_t)h * W_;
    size_t abase = ((size_t)bat * H_ + h) * W_ * L_;
    f32x4 acc[8][3] = {};
    for (int kb = 0; kb < 96; kb += 32) {
        #pragma unroll
        for (int i = 0; i < 4; ++i) {
            int u = tid + i * 512, row = u >> 2, seg = u & 3;
            int sg = (seg ^ FSW(row)) << 3;
            GLL16(&Vcm[vbase + (size_t)row * P_ + kb + sg], &Al[(size_t)u * 8]);
        }
        if (tid < 384) {
            int row = tid >> 2, seg = tid & 3;
            int sg = (seg ^ FSW(row)) << 3;
            GLL16(&attn[abase + (size_t)row * L_ + kb + sg], &Bl[(size_t)tid * 8]);
        }
        __syncthreads();
        int rr = lane & 15, gq = lane >> 4, ck = gq ^ FSW(rr);
        short8 fb[3];
        #pragma unroll
        for (int nt = 0; nt < 3; ++nt) fb[nt] = *(const short8*)&Bl[(wcn * 48 + nt * 16 + rr) * 32 + ck * 8];
        #pragma unroll
        for (int mt = 0; mt < 8; ++mt) {
            short8 fa = *(const short8*)&Al[(wrm * 128 + mt * 16 + rr) * 32 + ck * 8];
            #pragma unroll
            for (int nt = 0; nt < 3; ++nt)
                acc[mt][nt] = __builtin_amdgcn_mfma_f32_16x16x32_bf16(fa, fb[nt], acc[mt][nt], 0, 0, 0);
        }
        __syncthreads();
    }
    int rr = lane & 15, gq = lane >> 4;
    #pragma unroll
    for (int mt = 0; mt < 8; ++mt)
        #pragma unroll
        for (int nt = 0; nt < 3; ++nt) {
            int w = wcn * 48 + nt * 16 + rr;
            #pragma unroll
            for (int q = 0; q < 4; ++q) {
                int c = wrm * 128 + mt * 16 + gq * 4 + q;
                out0[((size_t)bat * C_ + c) * P_ + (size_t)h * W_ + w] = f2bf(acc[mt][nt][q]);
            }
        }
}

// ---------------- K9: out = x + gamma*(out0 + out1t^T), swizzled transpose LDS ----------------
__global__ __launch_bounds__(256) void k_final(const float* __restrict__ x, const ushort* __restrict__ out0,
                                               const ushort* __restrict__ out1t, const float* __restrict__ gamma,
                                               float* __restrict__ out) {
    __shared__ ushort t[96 * 128];                     // group-XOR swizzled [h][w] plane
    int c = blockIdx.x, bat = blockIdx.y;
    const ushort* src = out1t + ((size_t)bat * C_ + c) * P_;   // plane [w][h]
    int tid = threadIdx.x;
    #pragma unroll
    for (int k = 0; k < 9; ++k) {                      // 96 w x 24 us4 of h
        int u = tid + k * 256, w = u / 24, h4 = (u % 24) * 4;
        us4 v = *(const us4*)&src[w * 96 + h4];
        t[TSW(h4 + 0, w)] = v.x;
        t[TSW(h4 + 1, w)] = v.y;
        t[TSW(h4 + 2, w)] = v.z;
        t[TSW(h4 + 3, w)] = v.w;
    }
    __syncthreads();
    float gm = gamma[0];
    size_t base = ((size_t)bat * C_ + c) * P_;
    #pragma unroll
    for (int k = 0; k < 9; ++k) {                      // 96 h x 24 us4 of w
        int u = tid + k * 256, h = u / 24, w4 = (u % 24) * 4;
        size_t idx = base + h * W_ + w4;
        float4 xv = *(const float4*)&x[idx];
        us4 o0 = *(const us4*)&out0[idx];
        us4 o1 = *(const us4*)&t[TSW(h, w4)];
        float4 r;
        r.x = xv.x + gm * (bf2f(o0.x) + bf2f(o1.x));
        r.y = xv.y + gm * (bf2f(o0.y) + bf2f(o1.y));
        r.z = xv.z + gm * (bf2f(o0.z) + bf2f(o1.z));
        r.w = xv.w + gm * (bf2f(o0.w) + bf2f(o1.w));
        *(float4*)&out[idx] = r;
    }
}

extern "C" void kernel_launch(void* const* d_in, const int* in_sizes, int n_in,
                              void* d_out, int out_size, void* d_ws, size_t ws_size,
                              hipStream_t stream) {
    const float* x     = (const float*)d_in[0];
    const float* Wq    = (const float*)d_in[1];
    const float* bq    = (const float*)d_in[2];
    const float* Wk    = (const float*)d_in[3];
    const float* bk    = (const float*)d_in[4];
    const float* Wv    = (const float*)d_in[5];
    const float* bv    = (const float*)d_in[6];
    const float* gamma = (const float*)d_in[7];
    float* out = (float*)d_out;
    char* ws = (char*)d_ws;

    const size_t SZ  = (size_t)NP * C_ * 2;           // 75,497,472 B
    const size_t QKS = (size_t)NP * CQ_ * 2;          // 9,437,184 B
    ushort* xt     = (ushort*)(ws);
    ushort* out1t  = (ushort*)(ws);
    ushort* Vcm    = (ushort*)(ws + SZ);
    ushort* Vt     = (ushort*)(ws + 2 * SZ);
    ushort* out0   = Vt;
    ushort* Qb     = (ushort*)(ws + 3 * SZ);
    ushort* Kb     = (ushort*)(ws + 3 * SZ + QKS);
    ushort* attn   = (ushort*)(ws + 3 * SZ + 2 * QKS);
    size_t off_wall = 3 * SZ + 2 * QKS + (size_t)NP * L_ * 2;
    ushort* Wall   = (ushort*)(ws + off_wall);
    float*  ball   = (float*) (ws + off_wall + 640 * C_ * 2);

    k_wconv  <<<dim3(1280),       dim3(256),   0, stream>>>(Wq, Wk, Wv, bq, bk, bv, Wall, ball);
    k_xt     <<<dim3(144, 8, 8),  dim3(256),   0, stream>>>(x, xt);
    k_proj   <<<dim3(2880),       dim3(256),   0, stream>>>(xt, Wall, ball, Qb, Kb, Vcm);
    k_vt     <<<dim3(512, 8),     dim3(256),   0, stream>>>(Vcm, Vt);
    k_erow   <<<dim3(96, 8),      dim3(256),   0, stream>>>(Qb, Kb, attn);
    k_ecolsm <<<dim3(96, 8),      dim3(256),   0, stream>>>(Qb, Kb, attn);
    k_pvcol  <<<dim3(96, 8),      dim3(512),   0, stream>>>(Vt, attn, out1t);
    k_pvrow  <<<dim3(96, 8),      dim3(512),   0, stream>>>(Vcm, attn, out0);
    k_final  <<<dim3(512, 8),     dim3(256),   0, stream>>>(x, out0, out1t, gamma, out);
}

// Round 13
// 349.113 us; speedup vs baseline: 1.0282x; 1.0010x over previous
//
#include <hip/hip_runtime.h>
#include <stdint.h>

#define B_  8
#define C_  512
#define H_  96
#define W_  96
#define CQ_ 64
#define P_  (H_*W_)     // 9216 pixels per batch
#define NP  (B_*P_)     // 73728
#define L_  (W_+H_)     // 192 logits per pixel

typedef __attribute__((ext_vector_type(8))) short short8;
typedef __attribute__((ext_vector_type(4))) float f32x4;
typedef __attribute__((ext_vector_type(4))) unsigned short us4;

__device__ __forceinline__ ushort f2bf(float f) {
    uint32_t u = __builtin_bit_cast(uint32_t, f);
    u += 0x7fff + ((u >> 16) & 1);
    return (ushort)(u >> 16);
}
__device__ __forceinline__ float bf2f(ushort h) {
    uint32_t u = ((uint32_t)h) << 16;
    return __builtin_bit_cast(float, u);
}

// global -> LDS direct 16B copy (dest = wave-uniform base + lane*16)
#define GLL16(g, l) __builtin_amdgcn_global_load_lds( \
    (const __attribute__((address_space(1))) uint32_t*)(g), \
    (__attribute__((address_space(3))) uint32_t*)(l), 16, 0, 0)

// chunk swizzle for GEMM staging (proven r6): reads use ck = gq^FSW(rr)
#define FSW(r) (((r) >> 1) & 3)

// transpose-buffer group swizzle (r9): element (r,c) of a 96x96 plane at
// t[r*128 + (((c>>2) ^ ((r>>2)&7))<<2) + (c&3)]
__device__ __forceinline__ int TSW(int r, int c) {
    return r * 128 + ((((c >> 2) ^ ((r >> 2) & 7))) << 2) + (c & 3);
}

// ---------------- K0a: x (b,c,p) fp32 -> x_t (b,p,c) bf16 ----------------
__global__ __launch_bounds__(256) void k_xt(const float* __restrict__ x, ushort* __restrict__ xt) {
    __shared__ float tile[64 * 67];                    // pad 67: read bank-step 12 -> 2-way
    int p0 = blockIdx.x * 64, c0 = blockIdx.y * 64, bat = blockIdx.z;
    int tid = threadIdx.x;
    const float* xb = x + ((size_t)bat * C_ + c0) * P_ + p0;
    #pragma unroll
    for (int k = 0; k < 4; ++k) {                      // 64 c-rows x 16 float4
        int u = tid + k * 256, row = u >> 4, p4 = (u & 15) * 4;
        float4 v = *(const float4*)&xb[(size_t)row * P_ + p4];
        tile[row * 67 + p4]     = v.x;
        tile[row * 67 + p4 + 1] = v.y;
        tile[row * 67 + p4 + 2] = v.z;
        tile[row * 67 + p4 + 3] = v.w;
    }
    __syncthreads();
    ushort* o = xt + ((size_t)bat * P_ + p0) * C_ + c0;
    #pragma unroll
    for (int k = 0; k < 4; ++k) {                      // 64 p-rows x 16 us4 (c)
        int u = tid + k * 256, p = u >> 4, c4 = (u & 15) * 4;
        us4 v;
        v.x = f2bf(tile[(c4 + 0) * 67 + p]);
        v.y = f2bf(tile[(c4 + 1) * 67 + p]);
        v.z = f2bf(tile[(c4 + 2) * 67 + p]);
        v.w = f2bf(tile[(c4 + 3) * 67 + p]);
        *(us4*)&o[(size_t)p * C_ + c4] = v;
    }
}

// ---------------- K0b: weights -> bf16 combined [640][512]; ball[640] ----------------
__global__ __launch_bounds__(256) void k_wconv(const float* __restrict__ Wq, const float* __restrict__ Wk,
                                               const float* __restrict__ Wv, const float* __restrict__ bq,
                                               const float* __restrict__ bk, const float* __restrict__ bv,
                                               ushort* __restrict__ Wall, float* __restrict__ ball) {
    int idx = blockIdx.x * 256 + threadIdx.x;
    if (idx < 640) {
        float b;
        if (idx < 64)       b = bq[idx];
        else if (idx < 128) b = bk[idx - 64];
        else                b = bv[idx - 128];
        ball[idx] = b;
    }
    if (idx >= 640 * C_) return;
    int o = idx / C_, c = idx % C_;
    float v;
    if (o < 64)       v = Wq[o * C_ + c];
    else if (o < 128) v = Wk[(o - 64) * C_ + c];
    else              v = Wv[(o - 128) * C_ + c];
    Wall[idx] = f2bf(v);
}

// ---------------- K1: projection GEMM, 2-phase double-buffered (r12-proven). ----------------
__global__ __launch_bounds__(256, 4) void k_proj(const ushort* __restrict__ xt, const ushort* __restrict__ Wall,
                                                 const float* __restrict__ ball,
                                                 ushort* __restrict__ Qb, ushort* __restrict__ Kb,
                                                 ushort* __restrict__ Vcm) {
    __shared__ __align__(16) ushort SB[2][2 * 128 * 32];   // [buf][Al|Bl] 32KB
    ushort* Tl = &SB[0][0];                                 // [128][68] epilogue alias
    int tid = threadIdx.x, lane = tid & 63, wv = tid >> 6;
    int wr = wv >> 1, wc = wv & 1;
    int wg = ((int)blockIdx.x & 7) * 360 + ((int)blockIdx.x >> 3);
    int m0 = (wg % 5) * 128;
    int n0 = (wg / 5) * 128;
    f32x4 acc[4][4] = {};
    {
        ushort* Al = &SB[0][0]; ushort* Bl = &SB[0][128 * 32];
        #pragma unroll
        for (int i = 0; i < 2; ++i) {
            int u = tid + i * 256, row = u >> 2, seg = u & 3;
            int sg = (seg ^ FSW(row)) << 3;
            GLL16(&Wall[(size_t)(m0 + row) * C_ + sg], &Al[(size_t)u * 8]);
            GLL16(&xt[(size_t)(n0 + row) * C_ + sg],   &Bl[(size_t)u * 8]);
        }
    }
    __syncthreads();
    for (int t = 0; t < 16; ++t) {
        int cur = t & 1;
        if (t < 15) {
            int kb = (t + 1) * 32;
            ushort* Al = &SB[cur ^ 1][0]; ushort* Bl = &SB[cur ^ 1][128 * 32];
            #pragma unroll
            for (int i = 0; i < 2; ++i) {
                int u = tid + i * 256, row = u >> 2, seg = u & 3;
                int sg = (seg ^ FSW(row)) << 3;
                GLL16(&Wall[(size_t)(m0 + row) * C_ + kb + sg], &Al[(size_t)u * 8]);
                GLL16(&xt[(size_t)(n0 + row) * C_ + kb + sg],   &Bl[(size_t)u * 8]);
            }
        }
        const ushort* Al = &SB[cur][0];
        const ushort* Bl = &SB[cur][128 * 32];
        int rr = lane & 15, gq = lane >> 4, ck = gq ^ FSW(rr);
        short8 fb[4];
        #pragma unroll
        for (int nt = 0; nt < 4; ++nt) fb[nt] = *(const short8*)&Bl[(wc * 64 + nt * 16 + rr) * 32 + ck * 8];
        #pragma unroll
        for (int mt = 0; mt < 4; ++mt) {
            short8 fa = *(const short8*)&Al[(wr * 64 + mt * 16 + rr) * 32 + ck * 8];
            #pragma unroll
            for (int nt = 0; nt < 4; ++nt)
                acc[mt][nt] = __builtin_amdgcn_mfma_f32_16x16x32_bf16(fa, fb[nt], acc[mt][nt], 0, 0, 0);
        }
        __syncthreads();
    }
    int rr = lane & 15, gq = lane >> 4;
    int bat = n0 / P_, pb0 = n0 - bat * P_;
    if (m0 == 0) {
        #pragma unroll
        for (int pass = 0; pass < 2; ++pass) {
            __syncthreads();
            if (wr == pass) {
                #pragma unroll
                for (int mt = 0; mt < 4; ++mt)
                    #pragma unroll
                    for (int nt = 0; nt < 4; ++nt) {
                        int col = wc * 64 + nt * 16 + rr;
                        #pragma unroll
                        for (int q = 0; q < 4; ++q) {
                            int ol = mt * 16 + gq * 4 + q;           // 0..63
                            Tl[col * 68 + ol] = f2bf(acc[mt][nt][q] + ball[pass * 64 + ol]);
                        }
                    }
            }
            __syncthreads();
            ushort* dst = pass ? Kb : Qb;
            int p = tid >> 1, off = (tid & 1) * 32;
            #pragma unroll
            for (int j = 0; j < 8; ++j)
                *(us4*)&dst[(size_t)(n0 + p) * CQ_ + off + j * 4] = *(const us4*)&Tl[p * 68 + off + j * 4];
        }
    } else {
        #pragma unroll
        for (int mt = 0; mt < 4; ++mt)
            #pragma unroll
            for (int nt = 0; nt < 4; ++nt) {
                int col = wc * 64 + nt * 16 + rr;
                #pragma unroll
                for (int q = 0; q < 4; ++q) {
                    int o = m0 + wr * 64 + mt * 16 + gq * 4 + q;     // 128..639
                    int c = o - 128;
                    Vcm[((size_t)bat * C_ + c) * P_ + pb0 + col] = f2bf(acc[mt][nt][q] + ball[o]);
                }
            }
    }
}

// ---------------- K3: Vcm (b,c,h,w) -> Vt (b,w,c,h); one plane per block, swizzled LDS ----------------
__global__ __launch_bounds__(256) void k_vt(const ushort* __restrict__ Vcm, ushort* __restrict__ Vt) {
    __shared__ ushort t[96 * 128];                     // group-XOR swizzled plane
    int c = blockIdx.x, bat = blockIdx.y;
    const ushort* src = Vcm + ((size_t)(bat * C_ + c)) * P_;
    int tid = threadIdx.x;
    #pragma unroll
    for (int k = 0; k < 9; ++k) {                      // 96 h x 24 us4 of w
        int u = tid + k * 256, h = u / 24, w4 = (u % 24) * 4;
        us4 v = *(const us4*)&src[h * 96 + w4];
        t[TSW(h, w4)]     = v.x;
        t[TSW(h, w4) + 1] = v.y;
        t[TSW(h, w4) + 2] = v.z;
        t[TSW(h, w4) + 3] = v.w;
    }
    __syncthreads();
    #pragma unroll
    for (int k = 0; k < 9; ++k) {                      // 96 w x 24 us4 of h
        int u = tid + k * 256, w = u / 24, h4 = (u % 24) * 4;
        us4 o;
        o.x = t[TSW(h4 + 0, w)];
        o.y = t[TSW(h4 + 1, w)];
        o.z = t[TSW(h4 + 2, w)];
        o.w = t[TSW(h4 + 3, w)];
        *(us4*)&Vt[((size_t)(bat * W_ + w) * C_ + c) * H_ + h4] = o;
    }
}

// ---------------- K4: e_row. block (h,b): M=96(w) N=96(v) K=64; bf16 into attn[pix][0:96] ----------------
#define LSTR 40
__global__ __launch_bounds__(256) void k_erow(const ushort* __restrict__ Qb, const ushort* __restrict__ Kb,
                                              ushort* __restrict__ attn) {
    __shared__ __align__(16) ushort Al[96 * LSTR];
    __shared__ __align__(16) ushort Bl[96 * LSTR];
    int h = blockIdx.x, bat = blockIdx.y;
    int tid = threadIdx.x, lane = tid & 63, wvid = tid >> 6;
    int wr = wvid >> 1, wc = wvid & 1;                 // wave tile 48x48
    size_t base = ((size_t)bat * H_ + h) * W_;
    f32x4 acc[3][3] = {};
    for (int kb = 0; kb < CQ_; kb += 32) {
        for (int s = tid; s < 96 * 4; s += 256) {
            int row = s >> 2, seg = s & 3;
            *(short8*)&Al[row * LSTR + seg * 8] = *(const short8*)&Qb[(base + row) * CQ_ + kb + seg * 8];
            *(short8*)&Bl[row * LSTR + seg * 8] = *(const short8*)&Kb[(base + row) * CQ_ + kb + seg * 8];
        }
        __syncthreads();
        int rr = lane & 15, gq = lane >> 4;
        #pragma unroll
        for (int mt = 0; mt < 3; ++mt) {
            short8 fa = *(const short8*)&Al[(wr * 48 + mt * 16 + rr) * LSTR + gq * 8];
            #pragma unroll
            for (int nt = 0; nt < 3; ++nt) {
                short8 fb = *(const short8*)&Bl[(wc * 48 + nt * 16 + rr) * LSTR + gq * 8];
                acc[mt][nt] = __builtin_amdgcn_mfma_f32_16x16x32_bf16(fa, fb, acc[mt][nt], 0, 0, 0);
            }
        }
        __syncthreads();
    }
    int rr = lane & 15, gq = lane >> 4;
    #pragma unroll
    for (int mt = 0; mt < 3; ++mt)
        #pragma unroll
        for (int nt = 0; nt < 3; ++nt)
            #pragma unroll
            for (int q = 0; q < 4; ++q) {
                int w = wr * 48 + mt * 16 + gq * 4 + q;
                int v = wc * 48 + nt * 16 + rr;
                attn[(base + w) * L_ + v] = f2bf(acc[mt][nt][q]);
            }
}

// ---------------- K5: e_col GEMM + fused softmax (in-place on attn). block (w,b). ----------------
__global__ __launch_bounds__(256) void k_ecolsm(const ushort* __restrict__ Qb, const ushort* __restrict__ Kb,
                                                ushort* __restrict__ attn) {
    __shared__ __align__(16) ushort Al[96 * LSTR];
    __shared__ __align__(16) ushort Bl[96 * LSTR];
    __shared__ ushort ecl[96 * 100];                   // [h][g] bf16, padded
    int w = blockIdx.x, bat = blockIdx.y;
    int tid = threadIdx.x, lane = tid & 63, wvid = tid >> 6;
    int wr = wvid >> 1, wc = wvid & 1;
    f32x4 acc[3][3] = {};
    for (int kb = 0; kb < CQ_; kb += 32) {
        for (int s = tid; s < 96 * 4; s += 256) {
            int row = s >> 2, seg = s & 3;
            size_t px = ((size_t)bat * H_ + row) * W_ + w;
            *(short8*)&Al[row * LSTR + seg * 8] = *(const short8*)&Qb[px * CQ_ + kb + seg * 8];
            *(short8*)&Bl[row * LSTR + seg * 8] = *(const short8*)&Kb[px * CQ_ + kb + seg * 8];
        }
        __syncthreads();
        int rr = lane & 15, gq = lane >> 4;
        #pragma unroll
        for (int mt = 0; mt < 3; ++mt) {
            short8 fa = *(const short8*)&Al[(wr * 48 + mt * 16 + rr) * LSTR + gq * 8];
            #pragma unroll
            for (int nt = 0; nt < 3; ++nt) {
                short8 fb = *(const short8*)&Bl[(wc * 48 + nt * 16 + rr) * LSTR + gq * 8];
                acc[mt][nt] = __builtin_amdgcn_mfma_f32_16x16x32_bf16(fa, fb, acc[mt][nt], 0, 0, 0);
            }
        }
        __syncthreads();
    }
    {
        int rr = lane & 15, gq = lane >> 4;
        #pragma unroll
        for (int mt = 0; mt < 3; ++mt)
            #pragma unroll
            for (int nt = 0; nt < 3; ++nt)
                #pragma unroll
                for (int q = 0; q < 4; ++q) {
                    int hh = wr * 48 + mt * 16 + gq * 4 + q;
                    int gg = wc * 48 + nt * 16 + rr;
                    ecl[hh * 100 + gg] = f2bf(acc[mt][nt][q]);
                }
    }
    __syncthreads();
    for (int h = wvid; h < H_; h += 4) {
        size_t pix = ((size_t)bat * H_ + h) * W_ + w;
        ushort* ap = attn + pix * L_;
        float a  = bf2f(ap[lane]);
        float b  = (lane < 32) ? bf2f(ap[64 + lane]) : -1e30f;
        float c0 = bf2f(ecl[h * 100 + lane]);
        float c1 = (lane < 32) ? bf2f(ecl[h * 100 + 64 + lane]) : -1e30f;
        float m = fmaxf(fmaxf(a, b), fmaxf(c0, c1));
        #pragma unroll
        for (int off = 32; off; off >>= 1) m = fmaxf(m, __shfl_xor(m, off));
        float ea = __expf(a - m), eb = (lane < 32) ? __expf(b - m) : 0.0f;
        float ec0 = __expf(c0 - m), ec1 = (lane < 32) ? __expf(c1 - m) : 0.0f;
        float s = ea + eb + ec0 + ec1;
        #pragma unroll
        for (int off = 32; off; off >>= 1) s += __shfl_xor(s, off);
        float inv = 1.0f / s;
        ap[lane] = f2bf(ea * inv);
        ap[96 + lane] = f2bf(ec0 * inv);
        if (lane < 32) {
            ap[64 + lane] = f2bf(eb * inv);
            ap[160 + lane] = f2bf(ec1 * inv);
        }
    }
}

// ---------------- K8: col PV, 2-PHASE dbuf. block (w,b): M=512(c) N=96(h) K=96(g) ----------------
#define PVA (512 * 32)
#define PVB (96 * 32)
__global__ __launch_bounds__(512) void k_pvcol(const ushort* __restrict__ Vt, const ushort* __restrict__ attn,
                                               ushort* __restrict__ out1t) {
    __shared__ __align__(16) ushort SB[2][PVA + PVB];  // 2 x 38KB = 76KB
    int w = blockIdx.x, bat = blockIdx.y;
    int tid = threadIdx.x, lane = tid & 63, wvid = tid >> 6;
    int wrm = wvid >> 1, wcn = wvid & 1;              // 4m x 2n, wave tile 128x48
    size_t vbase = ((size_t)bat * W_ + w) * C_ * H_;
    size_t abase = ((size_t)bat * P_ + w) * L_ + W_;
    f32x4 acc[8][3] = {};
    {   // prologue: stage k-step 0
        ushort* Al = &SB[0][0]; ushort* Bl = &SB[0][PVA];
        #pragma unroll
        for (int i = 0; i < 4; ++i) {
            int u = tid + i * 512, row = u >> 2, seg = u & 3;
            int sg = (seg ^ FSW(row)) << 3;
            GLL16(&Vt[vbase + (size_t)row * H_ + sg], &Al[(size_t)u * 8]);
        }
        if (tid < 384) {
            int row = tid >> 2, seg = tid & 3;
            int sg = (seg ^ FSW(row)) << 3;
            GLL16(&attn[abase + (size_t)row * (W_ * L_) + sg], &Bl[(size_t)tid * 8]);
        }
    }
    __syncthreads();
    for (int t = 0; t < 3; ++t) {
        int cur = t & 1;
        if (t < 2) {                                   // prefetch next k-step before compute
            int kb = (t + 1) * 32;
            ushort* Al = &SB[cur ^ 1][0]; ushort* Bl = &SB[cur ^ 1][PVA];
            #pragma unroll
            for (int i = 0; i < 4; ++i) {
                int u = tid + i * 512, row = u >> 2, seg = u & 3;
                int sg = (seg ^ FSW(row)) << 3;
                GLL16(&Vt[vbase + (size_t)row * H_ + kb + sg], &Al[(size_t)u * 8]);
            }
            if (tid < 384) {
                int row = tid >> 2, seg = tid & 3;
                int sg = (seg ^ FSW(row)) << 3;
                GLL16(&attn[abase + (size_t)row * (W_ * L_) + kb + sg], &Bl[(size_t)tid * 8]);
            }
        }
        const ushort* Al = &SB[cur][0];
        const ushort* Bl = &SB[cur][PVA];
        int rr = lane & 15, gq = lane >> 4, ck = gq ^ FSW(rr);
        short8 fb[3];
        #pragma unroll
        for (int nt = 0; nt < 3; ++nt) fb[nt] = *(const short8*)&Bl[(wcn * 48 + nt * 16 + rr) * 32 + ck * 8];
        #pragma unroll
        for (int mt = 0; mt < 8; ++mt) {
            short8 fa = *(const short8*)&Al[(wrm * 128 + mt * 16 + rr) * 32 + ck * 8];
            #pragma unroll
            for (int nt = 0; nt < 3; ++nt)
                acc[mt][nt] = __builtin_amdgcn_mfma_f32_16x16x32_bf16(fa, fb[nt], acc[mt][nt], 0, 0, 0);
        }
        __syncthreads();
    }
    int rr = lane & 15, gq = lane >> 4;
    #pragma unroll
    for (int mt = 0; mt < 8; ++mt)
        #pragma unroll
        for (int nt = 0; nt < 3; ++nt) {
            int hh = wcn * 48 + nt * 16 + rr;
            #pragma unroll
            for (int q = 0; q < 4; ++q) {
                int c = wrm * 128 + mt * 16 + gq * 4 + q;
                out1t[((size_t)(bat * C_ + c) * W_ + w) * H_ + hh] = f2bf(acc[mt][nt][q]);
            }
        }
}

// ---------------- K7: row PV, 2-PHASE dbuf. block (h,b): M=512(c) N=96(w) K=96(v) ----------------
__global__ __launch_bounds__(512) void k_pvrow(const ushort* __restrict__ Vcm, const ushort* __restrict__ attn,
                                               ushort* __restrict__ out0) {
    __shared__ __align__(16) ushort SB[2][PVA + PVB];  // 2 x 38KB = 76KB
    int h = blockIdx.x, bat = blockIdx.y;
    int tid = threadIdx.x, lane = tid & 63, wvid = tid >> 6;
    int wrm = wvid >> 1, wcn = wvid & 1;
    size_t vbase = (size_t)bat * C_ * P_ + (size_t)h * W_;
    size_t abase = ((size_t)bat * H_ + h) * W_ * L_;
    f32x4 acc[8][3] = {};
    {   // prologue: stage k-step 0
        ushort* Al = &SB[0][0]; ushort* Bl = &SB[0][PVA];
        #pragma unroll
        for (int i = 0; i < 4; ++i) {
            int u = tid + i * 512, row = u >> 2, seg = u & 3;
            int sg = (seg ^ FSW(row)) << 3;
            GLL16(&Vcm[vbase + (size_t)row * P_ + sg], &Al[(size_t)u * 8]);
        }
        if (tid < 384) {
            int row = tid >> 2, seg = tid & 3;
            int sg = (seg ^ FSW(row)) << 3;
            GLL16(&attn[abase + (size_t)row * L_ + sg], &Bl[(size_t)tid * 8]);
        }
    }
    __syncthreads();
    for (int t = 0; t < 3; ++t) {
        int cur = t & 1;
        if (t < 2) {
            int kb = (t + 1) * 32;
            ushort* Al = &SB[cur ^ 1][0]; ushort* Bl = &SB[cur ^ 1][PVA];
            #pragma unroll
            for (int i = 0; i < 4; ++i) {
                int u = tid + i * 512, row = u >> 2, seg = u & 3;
                int sg = (seg ^ FSW(row)) << 3;
                GLL16(&Vcm[vbase + (size_t)row * P_ + kb + sg], &Al[(size_t)u * 8]);
            }
            if (tid < 384) {
                int row = tid >> 2, seg = tid & 3;
                int sg = (seg ^ FSW(row)) << 3;
                GLL16(&attn[abase + (size_t)row * L_ + kb + sg], &Bl[(size_t)tid * 8]);
            }
        }
        const ushort* Al = &SB[cur][0];
        const ushort* Bl = &SB[cur][PVA];
        int rr = lane & 15, gq = lane >> 4, ck = gq ^ FSW(rr);
        short8 fb[3];
        #pragma unroll
        for (int nt = 0; nt < 3; ++nt) fb[nt] = *(const short8*)&Bl[(wcn * 48 + nt * 16 + rr) * 32 + ck * 8];
        #pragma unroll
        for (int mt = 0; mt < 8; ++mt) {
            short8 fa = *(const short8*)&Al[(wrm * 128 + mt * 16 + rr) * 32 + ck * 8];
            #pragma unroll
            for (int nt = 0; nt < 3; ++nt)
                acc[mt][nt] = __builtin_amdgcn_mfma_f32_16x16x32_bf16(fa, fb[nt], acc[mt][nt], 0, 0, 0);
        }
        __syncthreads();
    }
    int rr = lane & 15, gq = lane >> 4;
    #pragma unroll
    for (int mt = 0; mt < 8; ++mt)
        #pragma unroll
        for (int nt = 0; nt < 3; ++nt) {
            int w = wcn * 48 + nt * 16 + rr;
            #pragma unroll
            for (int q = 0; q < 4; ++q) {
                int c = wrm * 128 + mt * 16 + gq * 4 + q;
                out0[((size_t)bat * C_ + c) * P_ + (size_t)h * W_ + w] = f2bf(acc[mt][nt][q]);
            }
        }
}

// ---------------- K9: out = x + gamma*(out0 + out1t^T), swizzled transpose LDS ----------------
__global__ __launch_bounds__(256) void k_final(const float* __restrict__ x, const ushort* __restrict__ out0,
                                               const ushort* __restrict__ out1t, const float* __restrict__ gamma,
                                               float* __restrict__ out) {
    __shared__ ushort t[96 * 128];                     // group-XOR swizzled [h][w] plane
    int c = blockIdx.x, bat = blockIdx.y;
    const ushort* src = out1t + ((size_t)bat * C_ + c) * P_;   // plane [w][h]
    int tid = threadIdx.x;
    #pragma unroll
    for (int k = 0; k < 9; ++k) {                      // 96 w x 24 us4 of h
        int u = tid + k * 256, w = u / 24, h4 = (u % 24) * 4;
        us4 v = *(const us4*)&src[w * 96 + h4];
        t[TSW(h4 + 0, w)] = v.x;
        t[TSW(h4 + 1, w)] = v.y;
        t[TSW(h4 + 2, w)] = v.z;
        t[TSW(h4 + 3, w)] = v.w;
    }
    __syncthreads();
    float gm = gamma[0];
    size_t base = ((size_t)bat * C_ + c) * P_;
    #pragma unroll
    for (int k = 0; k < 9; ++k) {                      // 96 h x 24 us4 of w
        int u = tid + k * 256, h = u / 24, w4 = (u % 24) * 4;
        size_t idx = base + h * W_ + w4;
        float4 xv = *(const float4*)&x[idx];
        us4 o0 = *(const us4*)&out0[idx];
        us4 o1 = *(const us4*)&t[TSW(h, w4)];
        float4 r;
        r.x = xv.x + gm * (bf2f(o0.x) + bf2f(o1.x));
        r.y = xv.y + gm * (bf2f(o0.y) + bf2f(o1.y));
        r.z = xv.z + gm * (bf2f(o0.z) + bf2f(o1.z));
        r.w = xv.w + gm * (bf2f(o0.w) + bf2f(o1.w));
        *(float4*)&out[idx] = r;
    }
}

extern "C" void kernel_launch(void* const* d_in, const int* in_sizes, int n_in,
                              void* d_out, int out_size, void* d_ws, size_t ws_size,
                              hipStream_t stream) {
    const float* x     = (const float*)d_in[0];
    const float* Wq    = (const float*)d_in[1];
    const float* bq    = (const float*)d_in[2];
    const float* Wk    = (const float*)d_in[3];
    const float* bk    = (const float*)d_in[4];
    const float* Wv    = (const float*)d_in[5];
    const float* bv    = (const float*)d_in[6];
    const float* gamma = (const float*)d_in[7];
    float* out = (float*)d_out;
    char* ws = (char*)d_ws;

    const size_t SZ  = (size_t)NP * C_ * 2;           // 75,497,472 B
    const size_t QKS = (size_t)NP * CQ_ * 2;          // 9,437,184 B
    ushort* xt     = (ushort*)(ws);
    ushort* out1t  = (ushort*)(ws);
    ushort* Vcm    = (ushort*)(ws + SZ);
    ushort* Vt     = (ushort*)(ws + 2 * SZ);
    ushort* out0   = Vt;
    ushort* Qb     = (ushort*)(ws + 3 * SZ);
    ushort* Kb     = (ushort*)(ws + 3 * SZ + QKS);
    ushort* attn   = (ushort*)(ws + 3 * SZ + 2 * QKS);
    size_t off_wall = 3 * SZ + 2 * QKS + (size_t)NP * L_ * 2;
    ushort* Wall   = (ushort*)(ws + off_wall);
    float*  ball   = (float*) (ws + off_wall + 640 * C_ * 2);

    k_wconv  <<<dim3(1280),       dim3(256),   0, stream>>>(Wq, Wk, Wv, bq, bk, bv, Wall, ball);
    k_xt     <<<dim3(144, 8, 8),  dim3(256),   0, stream>>>(x, xt);
    k_proj   <<<dim3(2880),       dim3(256),   0, stream>>>(xt, Wall, ball, Qb, Kb, Vcm);
    k_vt     <<<dim3(512, 8),     dim3(256),   0, stream>>>(Vcm, Vt);
    k_erow   <<<dim3(96, 8),      dim3(256),   0, stream>>>(Qb, Kb, attn);
    k_ecolsm <<<dim3(96, 8),      dim3(256),   0, stream>>>(Qb, Kb, attn);
    k_pvcol  <<<dim3(96, 8),      dim3(512),   0, stream>>>(Vt, attn, out1t);
    k_pvrow  <<<dim3(96, 8),      dim3(512),   0, stream>>>(Vcm, attn, out0);
    k_final  <<<dim3(512, 8),     dim3(256),   0, stream>>>(x, out0, out1t, gamma, out);
}